// Round 7
// baseline (178.418 us; speedup 1.0000x reference)
//
#include <hip/hip_runtime.h>
#include <stdint.h>
#include <stddef.h>

// Problem geometry (fixed by setup_inputs)
#define BROWS  16384   // inputs rows
#define SROWS  8192    // support vectors
#define FDIM   512     // features
#define NCHUNK 4       // S split (grid = NCHUNK * 64 = 256 blocks)
#define SCHUNK (SROWS / NCHUNK)     // 2048
#define BN     32                   // support cols per tile
#define NTILES (SCHUNK / BN)        // 64
#define BM     256                  // X rows per block (4 waves * 64 rows)
#define KSTEPS (FDIM / 16)          // 32 MFMA k-steps of 16

#define LOG2E 1.44269504088896340736f

typedef __bf16 bf16x8 __attribute__((ext_vector_type(8)));
typedef float  f32x16 __attribute__((ext_vector_type(16)));

__device__ inline void gload16(const void* g, void* l) {
  __builtin_amdgcn_global_load_lds(
      (const __attribute__((address_space(1))) void*)g,
      (__attribute__((address_space(3))) void*)l, 16, 0, 0);
}

// ---------------------------------------------------------------------------
// Prep: S f32 -> bf16 (row major), lc2[s] = log2(coeff[s]) - g*log2e*||s||^2
// so the main-kernel epilogue is exp2(K2*cross + lc2) (coeff mul folded in).
// ---------------------------------------------------------------------------
__global__ __launch_bounds__(256) void prep_s_kernel(
    const float* __restrict__ S, const float* __restrict__ coeff,
    const float* __restrict__ gamma, __bf16* __restrict__ Sb,
    float* __restrict__ lc2)
{
  const int lane = threadIdx.x & 63;
  const int wid  = threadIdx.x >> 6;
  const int row  = (blockIdx.x << 2) + wid;
  const float* src = S + ((size_t)row << 9) + (lane << 3);
  float4 a = ((const float4*)src)[0];
  float4 b = ((const float4*)src)[1];
  float sq = a.x*a.x + a.y*a.y + a.z*a.z + a.w*a.w +
             b.x*b.x + b.y*b.y + b.z*b.z + b.w*b.w;
  bf16x8 v;
  v[0]=(__bf16)a.x; v[1]=(__bf16)a.y; v[2]=(__bf16)a.z; v[3]=(__bf16)a.w;
  v[4]=(__bf16)b.x; v[5]=(__bf16)b.y; v[6]=(__bf16)b.z; v[7]=(__bf16)b.w;
  *(bf16x8*)(Sb + ((size_t)row << 9) + (lane << 3)) = v;
  #pragma unroll
  for (int m = 1; m < 64; m <<= 1) sq += __shfl_xor(sq, m, 64);
  if (lane == 0) {
    float g = gamma[0];
    lc2[row] = log2f(coeff[row]) - g * LOG2E * sq;
  }
}

// ---------------------------------------------------------------------------
// Main fused kernel.
// Block = 256 threads = 4 waves, 1 block/CU (VGPR-limited).
// Wave w owns 64 X rows as TWO 32-row MFMA tiles with full K=512 in registers
// (256 VGPR of A frags) -> each ds_read_b128 B-frag feeds 2 MFMAs, moving the
// structural ceiling from the LDS-read pipe to the MFMA pipe.
// B tile (32 cols x 512 k, bf16) double-buffered in LDS via global_load_lds;
// layout [kblock(64)][col(32)][16B] is linear for staging and conflict-free
// (additive immediate offsets) for ds_read_b128.
// Epilogue per tile: score += exp2(K2*cross + lc2[s]) (2 fma + exp + add).
// ---------------------------------------------------------------------------
__global__ __launch_bounds__(256, 1) void ocsvm_main_kernel(
    const float* __restrict__ X, const __bf16* __restrict__ Sb,
    const float* __restrict__ lc2, const float* __restrict__ gamma,
    float* __restrict__ partials)
{
  __shared__ char lds[65536];   // 2 buffers * 32 KB
  const int tid  = threadIdx.x;
  const int wid  = tid >> 6;
  const int lane = tid & 63;
  const int col  = lane & 31;
  const int half = lane >> 5;

  // XCD-affine mapping: blocks on the same XCD (blockIdx % 8) share one
  // 2 MB S-chunk -> fits the 4 MB per-XCD L2.
  const int bx    = blockIdx.x;
  const int xcd   = bx & 7;
  const int grp   = bx >> 3;
  const int chunk = xcd >> 1;
  const int mtile = (grp << 1) + (xcd & 1);
  const int m0    = mtile * BM;
  const int chunk0 = chunk * SCHUNK;

  const float gam = gamma[0];
  const float K2  = 2.0f * gam * LOG2E;   // exp(2g*cross) = exp2(K2*cross)

  // ---------- staging macro: 32 KB tile, 8 rounds of 256 threads * 16 B ----
#define STAGE(bufsel, tile)                                                   \
  {                                                                           \
    _Pragma("unroll")                                                         \
    for (int r = 0; r < 8; ++r) {                                             \
      const int t_all = (r << 8) + tid;                                       \
      const int cs = t_all & 31;                                              \
      const int kb = t_all >> 5;                                              \
      const char* src = (const char*)Sb +                                     \
          (((size_t)(chunk0 + ((tile) << 5) + cs)) << 10) + (kb << 4);        \
      char* dst = &lds[((bufsel) << 15) + (((r << 8) + (wid << 6)) << 4)];    \
      gload16(src, dst);                                                      \
    }                                                                         \
  }

  STAGE(0, 0);   // overlap tile-0 staging with the A-register load phase

  // ---------- A rows -> registers, 2 row-tiles, x_sq on the fly ----------
  // MFMA 32x32x16 A-frag: lane l -> row (l&31), k = 16*ks + 8*(l>>5) + [0..8)
  const float* xp0 = X + ((size_t)(m0 + (wid << 6) + col) << 9) + (half << 3);
  const float* xp1 = xp0 + (32u << 9);   // +32 rows
  bf16x8 af0[KSTEPS], af1[KSTEPS];
  float sq0 = 0.0f, sq1 = 0.0f;
  #pragma unroll
  for (int ks = 0; ks < KSTEPS; ++ks) {
    float4 a = *(const float4*)(xp0 + (ks << 4));
    float4 b = *(const float4*)(xp0 + (ks << 4) + 4);
    sq0 += a.x*a.x + a.y*a.y + a.z*a.z + a.w*a.w +
           b.x*b.x + b.y*b.y + b.z*b.z + b.w*b.w;
    bf16x8 v;
    v[0]=(__bf16)a.x; v[1]=(__bf16)a.y; v[2]=(__bf16)a.z; v[3]=(__bf16)a.w;
    v[4]=(__bf16)b.x; v[5]=(__bf16)b.y; v[6]=(__bf16)b.z; v[7]=(__bf16)b.w;
    af0[ks] = v;
    float4 c = *(const float4*)(xp1 + (ks << 4));
    float4 d = *(const float4*)(xp1 + (ks << 4) + 4);
    sq1 += c.x*c.x + c.y*c.y + c.z*c.z + c.w*c.w +
           d.x*d.x + d.y*d.y + d.z*d.z + d.w*d.w;
    bf16x8 w;
    w[0]=(__bf16)c.x; w[1]=(__bf16)c.y; w[2]=(__bf16)c.z; w[3]=(__bf16)c.w;
    w[4]=(__bf16)d.x; w[5]=(__bf16)d.y; w[6]=(__bf16)d.z; w[7]=(__bf16)d.w;
    af1[ks] = w;
  }
  sq0 += __shfl_xor(sq0, 32, 64);   // lanes l, l^32 cover the full row
  sq1 += __shfl_xor(sq1, 32, 64);
  const float e_x0 = __builtin_amdgcn_exp2f(-gam * LOG2E * sq0);
  const float e_x1 = __builtin_amdgcn_exp2f(-gam * LOG2E * sq1);

  __syncthreads();

  float score0[16], score1[16];
  #pragma unroll
  for (int i = 0; i < 16; ++i) { score0[i] = 0.0f; score1[i] = 0.0f; }

  // B-frag read: lane l -> col (l&31), k = 16*ks + 8*(l>>5) + [0..8)
  // LDS addr = (kblock*32 + col)*16, kblock = 2*ks + half  => base + ks*1024
  const char* bread0 = &lds[(half << 9) + (col << 4)];
  const float* lc2p = lc2 + chunk0 + col;

  for (int t = 0; t < NTILES; ++t) {
    if (t + 1 < NTILES) STAGE((t + 1) & 1, t + 1);

    const char* bb = bread0 + ((t & 1) << 15);
    f32x16 acc00 = {}, acc01 = {}, acc10 = {}, acc11 = {};
    #pragma unroll
    for (int ks = 0; ks < KSTEPS; ks += 2) {
      bf16x8 b0 = *(const bf16x8*)(bb + (ks << 10));
      bf16x8 b1 = *(const bf16x8*)(bb + ((ks + 1) << 10));
      acc00 = __builtin_amdgcn_mfma_f32_32x32x16_bf16(af0[ks],     b0, acc00, 0, 0, 0);
      acc10 = __builtin_amdgcn_mfma_f32_32x32x16_bf16(af1[ks],     b0, acc10, 0, 0, 0);
      acc01 = __builtin_amdgcn_mfma_f32_32x32x16_bf16(af0[ks + 1], b1, acc01, 0, 0, 0);
      acc11 = __builtin_amdgcn_mfma_f32_32x32x16_bf16(af1[ks + 1], b1, acc11, 0, 0, 0);
    }

    // epilogue: score += exp2(K2*cross + lc2[s])
    const float lc2v = lc2p[t << 5];
    #pragma unroll
    for (int r2 = 0; r2 < 16; ++r2) {
      score0[r2] += __builtin_amdgcn_exp2f(
          __builtin_fmaf(K2, acc00[r2], __builtin_fmaf(K2, acc01[r2], lc2v)));
      score1[r2] += __builtin_amdgcn_exp2f(
          __builtin_fmaf(K2, acc10[r2], __builtin_fmaf(K2, acc11[r2], lc2v)));
    }

    __syncthreads();   // staged tile landed; read-buffer free for overwrite
  }

  // ---------- fold cols, apply e_x, write chunk partials ----------
  // C layout (m74/m101): col = lane&31, row = (reg&3) + 8*(reg>>2) + 4*half
  #pragma unroll
  for (int r2 = 0; r2 < 16; ++r2) {
    float v0 = score0[r2];
    float v1 = score1[r2];
    #pragma unroll
    for (int m = 1; m < 32; m <<= 1) {
      v0 += __shfl_xor(v0, m, 64);
      v1 += __shfl_xor(v1, m, 64);
    }
    const int rloc = (r2 & 3) + ((r2 >> 2) << 3) + (half << 2);
    const float ex0 = __shfl(e_x0, rloc, 64);   // lane rloc holds row rloc's e_x
    const float ex1 = __shfl(e_x1, rloc, 64);
    if (col == 0) {
      float* dst = partials + chunk * BROWS + m0 + (wid << 6);
      dst[rloc]      = ex0 * v0;
      dst[32 + rloc] = ex1 * v1;
    }
  }
#undef STAGE
}

// ---------------------------------------------------------------------------
// Final: sum chunk partials, subtract rho.
// ---------------------------------------------------------------------------
__global__ __launch_bounds__(256) void reduce_kernel(
    const float* __restrict__ partials, const float* __restrict__ rho,
    float* __restrict__ out)
{
  const int i = blockIdx.x * 256 + threadIdx.x;
  float s = partials[i] + partials[BROWS + i] +
            partials[2 * BROWS + i] + partials[3 * BROWS + i];
  out[i] = s - rho[0];
}

extern "C" void kernel_launch(void* const* d_in, const int* in_sizes, int n_in,
                              void* d_out, int out_size, void* d_ws, size_t ws_size,
                              hipStream_t stream) {
  const float* X     = (const float*)d_in[0];   // [16384,512] f32
  const float* S     = (const float*)d_in[1];   // [8192,512]  f32
  const float* coeff = (const float*)d_in[2];   // [1,8192]    f32
  const float* rho   = (const float*)d_in[3];   // [1]         f32
  const float* gamma = (const float*)d_in[4];   // scalar      f32
  float* out = (float*)d_out;

  // ws layout: Sb bf16 (8 MB) | lc2 (32 KB) | partials (256 KB)
  char* ws = (char*)d_ws;
  __bf16* Sb    = (__bf16*)ws;
  float*  lc2   = (float*)(ws + (size_t)SROWS * FDIM * 2);
  float*  parts = (float*)(ws + (size_t)SROWS * FDIM * 2 + SROWS * 4);

  prep_s_kernel<<<SROWS / 4, 256, 0, stream>>>(S, coeff, gamma, Sb, lc2);
  ocsvm_main_kernel<<<NCHUNK * 64, 256, 0, stream>>>(X, Sb, lc2, gamma, parts);
  reduce_kernel<<<BROWS / 256, 256, 0, stream>>>(parts, rho, out);
}

// Round 8
// 151.415 us; speedup vs baseline: 1.1783x; 1.1783x over previous
//
#include <hip/hip_runtime.h>
#include <stdint.h>
#include <stddef.h>

// Problem geometry (fixed by setup_inputs)
#define BROWS  16384   // inputs rows
#define SROWS  8192    // support vectors
#define FDIM   512     // features
#define NCHUNK 4       // S split (grid = NCHUNK * 64 = 256 blocks)
#define SCHUNK (SROWS / NCHUNK)     // 2048
#define BN     32                   // support cols per tile
#define NTILES (SCHUNK / BN)        // 64
#define BM     256                  // X rows per block (8 waves * 32 rows)
#define KSTEPS (FDIM / 16)          // 32 MFMA k-steps of 16

#define LOG2E 1.44269504088896340736f

typedef __bf16 bf16x8 __attribute__((ext_vector_type(8)));
typedef float  f32x16 __attribute__((ext_vector_type(16)));

__device__ inline void gload16(const void* g, void* l) {
  __builtin_amdgcn_global_load_lds(
      (const __attribute__((address_space(1))) void*)g,
      (__attribute__((address_space(3))) void*)l, 16, 0, 0);
}

// ---------------------------------------------------------------------------
// Prep: S f32 -> bf16 (row major), lc2[s] = log2(coeff[s]) - g*log2e*||s||^2
// (validated in R7: absmax 4.0)
// ---------------------------------------------------------------------------
__global__ __launch_bounds__(256) void prep_s_kernel(
    const float* __restrict__ S, const float* __restrict__ coeff,
    const float* __restrict__ gamma, __bf16* __restrict__ Sb,
    float* __restrict__ lc2)
{
  const int lane = threadIdx.x & 63;
  const int wid  = threadIdx.x >> 6;
  const int row  = (blockIdx.x << 2) + wid;
  const float* src = S + ((size_t)row << 9) + (lane << 3);
  float4 a = ((const float4*)src)[0];
  float4 b = ((const float4*)src)[1];
  float sq = a.x*a.x + a.y*a.y + a.z*a.z + a.w*a.w +
             b.x*b.x + b.y*b.y + b.z*b.z + b.w*b.w;
  bf16x8 v;
  v[0]=(__bf16)a.x; v[1]=(__bf16)a.y; v[2]=(__bf16)a.z; v[3]=(__bf16)a.w;
  v[4]=(__bf16)b.x; v[5]=(__bf16)b.y; v[6]=(__bf16)b.z; v[7]=(__bf16)b.w;
  *(bf16x8*)(Sb + ((size_t)row << 9) + (lane << 3)) = v;
  #pragma unroll
  for (int m = 1; m < 64; m <<= 1) sq += __shfl_xor(sq, m, 64);
  if (lane == 0) {
    float g = gamma[0];
    lc2[row] = log2f(coeff[row]) - g * LOG2E * sq;
  }
}

// ---------------------------------------------------------------------------
// Main fused kernel — R0 8-wave structure + T4 counted-vmcnt pipeline.
// Block = 512 threads = 8 waves, wave w owns 32 X rows, full K=512 A-frags
// in registers. B tile (32 cols x 512 k) TRIPLE-buffered in LDS (3 x 32 KB);
// per tile: stage t+1, s_waitcnt vmcnt(4) (own t-loads done, t+1's 4 stay in
// flight ACROSS the barrier), raw s_barrier, then ds_read+MFMA+epilogue.
// Never vmcnt(0) in the main loop -> no staging-queue drain stall.
// Buffer safety: buf t%3 re-staged only at iter t+2; passing barrier t+1
// implies every wave consumed its iter-t reads (epilogue depends on MFMAs).
// ---------------------------------------------------------------------------
__global__ __launch_bounds__(512, 2) void ocsvm_main_kernel(
    const float* __restrict__ X, const __bf16* __restrict__ Sb,
    const float* __restrict__ lc2, const float* __restrict__ gamma,
    float* __restrict__ partials)
{
  __shared__ char lds[98304];   // 3 buffers * 32 KB
  const int tid  = threadIdx.x;
  const int wid  = tid >> 6;
  const int lane = tid & 63;
  const int col  = lane & 31;
  const int half = lane >> 5;

  // XCD-affine mapping: blocks on the same XCD (blockIdx % 8) share one
  // 2 MB S-chunk -> per-XCD L2 locality.
  const int bx    = blockIdx.x;
  const int xcd   = bx & 7;
  const int grp   = bx >> 3;
  const int chunk = xcd >> 1;
  const int mtile = (grp << 1) + (xcd & 1);
  const int m0    = mtile * BM;
  const int chunk0 = chunk * SCHUNK;

  const float gam = gamma[0];
  const float K2  = 2.0f * gam * LOG2E;   // exp(2g*cross) = exp2(K2*cross)

  // ---------- staging macro: 32 KB tile, 4 rounds of 512 threads * 16 B ----
  // linear LDS offset t_all*16 == [kb=t_all>>5][col=t_all&31][16B]
#define STAGE(bufsel, tile)                                                   \
  {                                                                           \
    _Pragma("unroll")                                                         \
    for (int r = 0; r < 4; ++r) {                                             \
      const int t_all = (r << 9) + tid;                                       \
      const int cs = t_all & 31;                                              \
      const int kb = t_all >> 5;                                              \
      const char* src = (const char*)Sb +                                     \
          (((size_t)(chunk0 + ((tile) << 5) + cs)) << 10) + (kb << 4);        \
      char* dst = &lds[(bufsel) * 32768 + (((r << 9) + (wid << 6)) << 4)];    \
      gload16(src, dst);                                                      \
    }                                                                         \
  }

  STAGE(0, 0);   // overlap tile-0 staging with the A-register load phase

  // ---------- A rows -> registers, x_sq on the fly ----------
  // MFMA 32x32x16 A-frag: lane l -> row (l&31), k = 16*ks + 8*(l>>5) + [0..8)
  const int arow = m0 + (wid << 5) + col;
  const float* xp = X + ((size_t)arow << 9) + (half << 3);
  bf16x8 afrag[KSTEPS];
  float sq = 0.0f;
  #pragma unroll
  for (int ks = 0; ks < KSTEPS; ++ks) {
    float4 a = *(const float4*)(xp + (ks << 4));
    float4 b = *(const float4*)(xp + (ks << 4) + 4);
    sq += a.x*a.x + a.y*a.y + a.z*a.z + a.w*a.w +
          b.x*b.x + b.y*b.y + b.z*b.z + b.w*b.w;
    bf16x8 v;
    v[0]=(__bf16)a.x; v[1]=(__bf16)a.y; v[2]=(__bf16)a.z; v[3]=(__bf16)a.w;
    v[4]=(__bf16)b.x; v[5]=(__bf16)b.y; v[6]=(__bf16)b.z; v[7]=(__bf16)b.w;
    afrag[ks] = v;
  }
  sq += __shfl_xor(sq, 32, 64);            // lanes l, l^32 cover the full row
  const float e_x = __builtin_amdgcn_exp2f(-gam * LOG2E * sq);

  float scoreAcc[16];
  #pragma unroll
  for (int i = 0; i < 16; ++i) scoreAcc[i] = 0.0f;

  // B-frag read: lane l -> col (l&31), k = 16*ks + 8*(l>>5) + [0..8)
  // LDS addr = (kblock*32 + col)*16, kblock = 2*ks + half  => base + ks*1024
  const char* bread0 = &lds[(half << 9) + (col << 4)];
  const float* lc2p = lc2 + chunk0 + col;

  int cur = 0;
  for (int t = 0; t < NTILES; ++t) {
    int nxt = cur + 1; if (nxt == 3) nxt = 0;
    if (t + 1 < NTILES) {
      STAGE(nxt, t + 1);
      // own tile-t loads complete; tile-(t+1)'s 4 loads stay in flight
      asm volatile("s_waitcnt vmcnt(4)" ::: "memory");
    } else {
      asm volatile("s_waitcnt vmcnt(0)" ::: "memory");
    }
    __builtin_amdgcn_s_barrier();     // all waves' tile-t loads landed
    asm volatile("" ::: "memory");    // fence: no ds_read hoists above barrier

    const char* bb = bread0 + cur * 32768;
    f32x16 acc0 = {};
    f32x16 acc1 = {};
    #pragma unroll
    for (int ks = 0; ks < KSTEPS; ks += 2) {
      bf16x8 b0 = *(const bf16x8*)(bb + (ks << 10));
      bf16x8 b1 = *(const bf16x8*)(bb + ((ks + 1) << 10));
      acc0 = __builtin_amdgcn_mfma_f32_32x32x16_bf16(afrag[ks],     b0, acc0, 0, 0, 0);
      acc1 = __builtin_amdgcn_mfma_f32_32x32x16_bf16(afrag[ks + 1], b1, acc1, 0, 0, 0);
    }

    // epilogue: scoreAcc += exp2(K2*cross + lc2[s])   (consumes all MFMAs ->
    // by the next barrier every wave's buf-t reads are retired)
    const float lc2v = lc2p[t << 5];
    #pragma unroll
    for (int r2 = 0; r2 < 16; ++r2) {
      scoreAcc[r2] += __builtin_amdgcn_exp2f(
          __builtin_fmaf(K2, acc0[r2], __builtin_fmaf(K2, acc1[r2], lc2v)));
    }
    cur = nxt;
  }

  // ---------- fold cols, apply e_x, write chunk partial ----------
  // C layout (m74/m101): col = lane&31, row = (reg&3) + 8*(reg>>2) + 4*half
  #pragma unroll
  for (int r2 = 0; r2 < 16; ++r2) {
    float v = scoreAcc[r2];
    v += __shfl_xor(v, 1, 64);
    v += __shfl_xor(v, 2, 64);
    v += __shfl_xor(v, 4, 64);
    v += __shfl_xor(v, 8, 64);
    v += __shfl_xor(v, 16, 64);
    const int rloc = (r2 & 3) + ((r2 >> 2) << 3) + (half << 2);
    const float exr = __shfl(e_x, rloc, 64);   // lane rloc holds row rloc's e_x
    if (col == 0)
      partials[chunk * BROWS + m0 + (wid << 5) + rloc] = exr * v;
  }
#undef STAGE
}

// ---------------------------------------------------------------------------
// Final: sum chunk partials, subtract rho.
// ---------------------------------------------------------------------------
__global__ __launch_bounds__(256) void reduce_kernel(
    const float* __restrict__ partials, const float* __restrict__ rho,
    float* __restrict__ out)
{
  const int i = blockIdx.x * 256 + threadIdx.x;
  float s = partials[i] + partials[BROWS + i] +
            partials[2 * BROWS + i] + partials[3 * BROWS + i];
  out[i] = s - rho[0];
}

extern "C" void kernel_launch(void* const* d_in, const int* in_sizes, int n_in,
                              void* d_out, int out_size, void* d_ws, size_t ws_size,
                              hipStream_t stream) {
  const float* X     = (const float*)d_in[0];   // [16384,512] f32
  const float* S     = (const float*)d_in[1];   // [8192,512]  f32
  const float* coeff = (const float*)d_in[2];   // [1,8192]    f32
  const float* rho   = (const float*)d_in[3];   // [1]         f32
  const float* gamma = (const float*)d_in[4];   // scalar      f32
  float* out = (float*)d_out;

  // ws layout: Sb bf16 (8 MB) | lc2 (32 KB) | partials (256 KB)
  char* ws = (char*)d_ws;
  __bf16* Sb    = (__bf16*)ws;
  float*  lc2   = (float*)(ws + (size_t)SROWS * FDIM * 2);
  float*  parts = (float*)(ws + (size_t)SROWS * FDIM * 2 + SROWS * 4);

  prep_s_kernel<<<SROWS / 4, 256, 0, stream>>>(S, coeff, gamma, Sb, lc2);
  ocsvm_main_kernel<<<NCHUNK * 64, 512, 0, stream>>>(X, Sb, lc2, gamma, parts);
  reduce_kernel<<<BROWS / 256, 256, 0, stream>>>(parts, rho, out);
}